// Round 1
// baseline (306.730 us; speedup 1.0000x reference)
//
#include <hip/hip_runtime.h>
#include <hip/hip_bf16.h>

typedef __bf16 bf16;
typedef __bf16 bf16x4 __attribute__((ext_vector_type(4)));
typedef __bf16 bf16x8 __attribute__((ext_vector_type(8)));
typedef float f32x4 __attribute__((ext_vector_type(4)));

// ---------------------------------------------------------------------------
// async global->LDS, 16B per lane. LDS dest must be wave-uniform base;
// HW adds lane*16. (guide §5: width=16 is the +67% lever)
// ---------------------------------------------------------------------------
__device__ __forceinline__ void gld_lds16(const void* g, void* l) {
  __builtin_amdgcn_global_load_lds(
      (const __attribute__((address_space(1))) void*)g,
      (__attribute__((address_space(3))) void*)l, 16, 0, 0);
}

// ---------------------------------------------------------------------------
// fp32 -> bf16 convert, 4 elems/thread
// ---------------------------------------------------------------------------
__global__ __launch_bounds__(256) void cvt_kernel(const float* __restrict__ src,
                                                  bf16* __restrict__ dst, int n4) {
  int i = blockIdx.x * 256 + threadIdx.x;
  if (i < n4) {
    float4 v = ((const float4*)src)[i];
    bf16x4 o = { (bf16)v.x, (bf16)v.y, (bf16)v.z, (bf16)v.w };
    ((bf16x4*)dst)[i] = o;
  }
}

// ---------------------------------------------------------------------------
// [R][C] fp32  ->  [C][R] bf16   (weights to K-major for MFMA B-fragments)
// ---------------------------------------------------------------------------
__global__ __launch_bounds__(256) void transpose_cvt_kernel(const float* __restrict__ src,
                                                            bf16* __restrict__ dst,
                                                            int R, int C) {
  __shared__ float tile[32][33];
  int tx = threadIdx.x & 31, ty = threadIdx.x >> 5;  // 32 x 8
  int bx = blockIdx.x * 32, by = blockIdx.y * 32;
#pragma unroll
  for (int j = 0; j < 32; j += 8)
    tile[ty + j][tx] = src[(size_t)(by + ty + j) * C + bx + tx];
  __syncthreads();
#pragma unroll
  for (int j = 0; j < 32; j += 8)
    dst[(size_t)(bx + ty + j) * R + by + tx] = (bf16)tile[tx][ty + j];
}

// ---------------------------------------------------------------------------
// m97-structure GEMM: C[M,N] = A[M,K] * BT[N,K]^T   (bf16 in, fp32 acc)
// 128x128 tile, BK=32, 256 thr = 2x2 waves, each wave 64x64 = 4x4 frags.
// MODE 1: scatter into Q [BH][T][64], K [BH][T][64], V^T [BH][64][T]
// MODE 2: plain fp32 store to Cf
// ---------------------------------------------------------------------------
template <int MODE>
__global__ __launch_bounds__(256) void gemm_kernel(
    const bf16* __restrict__ A, const bf16* __restrict__ BT,
    float* __restrict__ Cf, bf16* __restrict__ qb, bf16* __restrict__ kb,
    bf16* __restrict__ vt, int M, int N, int K) {
  __shared__ bf16 As[128 * 32];
  __shared__ bf16 Bs[128 * 32];
  const int t = threadIdx.x;
  const int w = t >> 6, l = t & 63;
  const int bm = blockIdx.y * 128, bn = blockIdx.x * 128;
  const int wr = (w >> 1) * 64, wc = (w & 1) * 64;
  const int lr = l & 15, lh = l >> 4;
  f32x4 acc[4][4] = {};

  const bf16* Ab = A + (size_t)bm * K;
  const bf16* Bb = BT + (size_t)bn * K;
  const int srow = t >> 2;         // 0..63
  const int scol = (t & 3) * 8;    // element col within BK
  char* AsB = (char*)As;
  char* BsB = (char*)Bs;
  const int ldsw = w * 1024;       // wave-uniform byte base

  for (int k0 = 0; k0 < K; k0 += 32) {
    __syncthreads();
    gld_lds16(Ab + (size_t)srow * K + k0 + scol, AsB + ldsw);
    gld_lds16(Ab + (size_t)(srow + 64) * K + k0 + scol, AsB + 4096 + ldsw);
    gld_lds16(Bb + (size_t)srow * K + k0 + scol, BsB + ldsw);
    gld_lds16(Bb + (size_t)(srow + 64) * K + k0 + scol, BsB + 4096 + ldsw);
    __syncthreads();
    bf16x8 af[4], bfr[4];
#pragma unroll
    for (int m = 0; m < 4; ++m)
      af[m] = *(const bf16x8*)(AsB + (wr + m * 16 + lr) * 64 + lh * 16);
#pragma unroll
    for (int n = 0; n < 4; ++n)
      bfr[n] = *(const bf16x8*)(BsB + (wc + n * 16 + lr) * 64 + lh * 16);
#pragma unroll
    for (int m = 0; m < 4; ++m)
#pragma unroll
      for (int n = 0; n < 4; ++n)
        acc[m][n] = __builtin_amdgcn_mfma_f32_16x16x32_bf16(af[m], bfr[n],
                                                            acc[m][n], 0, 0, 0);
  }

  const int r0 = bm + wr + (lh << 2);
  const int c0 = bn + wc + lr;
#pragma unroll
  for (int m = 0; m < 4; ++m) {
#pragma unroll
    for (int n = 0; n < 4; ++n) {
#pragma unroll
      for (int r = 0; r < 4; ++r) {
        float v = acc[m][n][r];
        int row = r0 + m * 16 + r;
        int col = c0 + n * 16;
        if (MODE == 2) {
          Cf[(size_t)row * N + col] = v;
        } else {
          int bb = row >> 11, tt = row & 2047;
          if (col < 1024) {
            int h = col >> 6, d = col & 63;
            qb[(((size_t)(bb * 16 + h)) * 2048 + tt) * 64 + d] = (bf16)v;
          } else if (col < 2048) {
            int c = col - 1024, h = c >> 6, d = c & 63;
            kb[(((size_t)(bb * 16 + h)) * 2048 + tt) * 64 + d] = (bf16)v;
          } else {
            int c = col - 2048, h = c >> 6, d = c & 63;
            vt[(((size_t)(bb * 16 + h)) * 64 + d) * 2048 + tt] = (bf16)v;
          }
        }
      }
    }
  }
}

// ---------------------------------------------------------------------------
// Causal flash attention.
// grid (16, 32): x = q-tile of 128 rows, y = b*16+h. 256 thr = 4 waves,
// wave w owns 32 q-rows. KV step = 32. K/V read direct from global (L2-fit).
// S fragments: row=(l>>4)*4+reg (q), col=l&15 (kv). Softmax rows reduce over
// the 16-lane col group. P re-layout via padded per-wave LDS tile.
// ---------------------------------------------------------------------------
__global__ __launch_bounds__(256) void attn_kernel(const bf16* __restrict__ qb,
                                                   const bf16* __restrict__ kb,
                                                   const bf16* __restrict__ vt,
                                                   bf16* __restrict__ ao) {
  __shared__ bf16 plds[4][32][40];  // +8 pad: 16B-aligned rows, ~2-way banks
  const int bh = blockIdx.y;
  const int q0 = blockIdx.x * 128;
  const int w = threadIdx.x >> 6, l = threadIdx.x & 63;
  const int qw = q0 + w * 32;
  const int lr = l & 15, lh = l >> 4;
  const bf16* Qh = qb + (size_t)bh * 2048 * 64;
  const bf16* Kh = kb + (size_t)bh * 2048 * 64;
  const bf16* Vh = vt + (size_t)bh * 64 * 2048;

  bf16x8 qf[2][2];
#pragma unroll
  for (int m = 0; m < 2; ++m)
#pragma unroll
    for (int c = 0; c < 2; ++c)
      qf[m][c] = *(const bf16x8*)(Qh + (size_t)(qw + m * 16 + lr) * 64 + c * 32 + lh * 8);

  f32x4 O[2][4] = {};
  float mrun[2][4], srun[2][4];
#pragma unroll
  for (int m = 0; m < 2; ++m)
#pragma unroll
    for (int r = 0; r < 4; ++r) { mrun[m][r] = -1e30f; srun[m][r] = 0.f; }

  const int lastkt = qw >> 5;
  for (int kt = 0; kt <= lastkt; ++kt) {
    const int kv0 = kt << 5;
    bf16x8 kf[2][2];
#pragma unroll
    for (int n2 = 0; n2 < 2; ++n2)
#pragma unroll
      for (int c = 0; c < 2; ++c)
        kf[n2][c] = *(const bf16x8*)(Kh + (size_t)(kv0 + n2 * 16 + lr) * 64 + c * 32 + lh * 8);

    f32x4 S[2][2] = {};
#pragma unroll
    for (int m = 0; m < 2; ++m)
#pragma unroll
      for (int n2 = 0; n2 < 2; ++n2) {
        S[m][n2] = __builtin_amdgcn_mfma_f32_16x16x32_bf16(qf[m][0], kf[n2][0], S[m][n2], 0, 0, 0);
        S[m][n2] = __builtin_amdgcn_mfma_f32_16x16x32_bf16(qf[m][1], kf[n2][1], S[m][n2], 0, 0, 0);
      }

    const bool diag = (kt == lastkt);
#pragma unroll
    for (int m = 0; m < 2; ++m)
#pragma unroll
      for (int n2 = 0; n2 < 2; ++n2)
#pragma unroll
        for (int r = 0; r < 4; ++r) {
          float s = S[m][n2][r] * 0.125f;
          if (diag) {
            int qg = m * 16 + lh * 4 + r;  // relative to qw; kv0==qw on diag
            int kg = n2 * 16 + lr;
            if (kg > qg) s = -1e30f;
          }
          S[m][n2][r] = s;
        }

#pragma unroll
    for (int m = 0; m < 2; ++m) {
#pragma unroll
      for (int r = 0; r < 4; ++r) {
        float v = fmaxf(S[m][0][r], S[m][1][r]);
#pragma unroll
        for (int d = 1; d < 16; d <<= 1) v = fmaxf(v, __shfl_xor(v, d, 64));
        float mn = fmaxf(mrun[m][r], v);
        float al = __expf(mrun[m][r] - mn);
        mrun[m][r] = mn;
        float p0 = __expf(S[m][0][r] - mn);
        float p1 = __expf(S[m][1][r] - mn);
        S[m][0][r] = p0;
        S[m][1][r] = p1;
        float rs = p0 + p1;
#pragma unroll
        for (int d = 1; d < 16; d <<= 1) rs += __shfl_xor(rs, d, 64);
        srun[m][r] = srun[m][r] * al + rs;
#pragma unroll
        for (int n = 0; n < 4; ++n) O[m][n][r] *= al;
      }
    }

    // P -> LDS (D-layout) -> A-fragment layout
#pragma unroll
    for (int m = 0; m < 2; ++m)
#pragma unroll
      for (int n2 = 0; n2 < 2; ++n2)
#pragma unroll
        for (int r = 0; r < 4; ++r)
          plds[w][m * 16 + lh * 4 + r][n2 * 16 + lr] = (bf16)S[m][n2][r];

    bf16x8 pf[2], vf[4];
#pragma unroll
    for (int m = 0; m < 2; ++m)
      pf[m] = *(const bf16x8*)&plds[w][m * 16 + lr][lh * 8];
#pragma unroll
    for (int n = 0; n < 4; ++n)
      vf[n] = *(const bf16x8*)(Vh + (size_t)(n * 16 + lr) * 2048 + kv0 + lh * 8);
#pragma unroll
    for (int m = 0; m < 2; ++m)
#pragma unroll
      for (int n = 0; n < 4; ++n)
        O[m][n] = __builtin_amdgcn_mfma_f32_16x16x32_bf16(pf[m], vf[n], O[m][n], 0, 0, 0);
  }

  const int bb = bh >> 4, h = bh & 15;
#pragma unroll
  for (int m = 0; m < 2; ++m)
#pragma unroll
    for (int n = 0; n < 4; ++n)
#pragma unroll
      for (int r = 0; r < 4; ++r) {
        float v = O[m][n][r] / srun[m][r];
        int tt = qw + m * 16 + lh * 4 + r;
        ao[((size_t)(bb * 2048 + tt)) * 1024 + h * 64 + n * 16 + lr] = (bf16)v;
      }
}

// ---------------------------------------------------------------------------
// launch
// ---------------------------------------------------------------------------
extern "C" void kernel_launch(void* const* d_in, const int* in_sizes, int n_in,
                              void* d_out, int out_size, void* d_ws, size_t ws_size,
                              hipStream_t stream) {
  const float* x = (const float*)d_in[0];
  // d_in[1] = mask (causal tril) — implemented analytically
  const float* Wqkv = (const float*)d_in[2];
  const float* Wout = (const float*)d_in[3];
  float* out = (float*)d_out;

  char* ws = (char*)d_ws;
  bf16* xb  = (bf16*)(ws);                        // 8 MB  [4096][1024]
  bf16* wqT = (bf16*)(ws + (size_t)(8 << 20));    // 6 MB  [3072][1024]
  bf16* woT = (bf16*)(ws + (size_t)(14 << 20));   // 2 MB  [1024][1024]
  bf16* qb  = (bf16*)(ws + (size_t)(16 << 20));   // 8 MB  [32][2048][64]
  bf16* kb  = (bf16*)(ws + (size_t)(24 << 20));   // 8 MB  [32][2048][64]
  bf16* vt  = (bf16*)(ws + (size_t)(32 << 20));   // 8 MB  [32][64][2048]
  bf16* ao  = (bf16*)(ws + (size_t)(40 << 20));   // 8 MB  [4096][1024]

  cvt_kernel<<<dim3(4096), dim3(256), 0, stream>>>(x, xb, 1048576);
  transpose_cvt_kernel<<<dim3(96, 32), dim3(256), 0, stream>>>(Wqkv, wqT, 1024, 3072);
  transpose_cvt_kernel<<<dim3(32, 32), dim3(256), 0, stream>>>(Wout, woT, 1024, 1024);
  gemm_kernel<1><<<dim3(24, 32), dim3(256), 0, stream>>>(xb, wqT, nullptr, qb, kb, vt,
                                                         4096, 3072, 1024);
  attn_kernel<<<dim3(16, 32), dim3(256), 0, stream>>>(qb, kb, vt, ao);
  gemm_kernel<2><<<dim3(8, 32), dim3(256), 0, stream>>>(ao, woT, out, nullptr, nullptr,
                                                        nullptr, 4096, 1024, 1024);
}

// Round 2
// 273.730 us; speedup vs baseline: 1.1206x; 1.1206x over previous
//
#include <hip/hip_runtime.h>
#include <hip/hip_bf16.h>

typedef __bf16 bf16;
typedef __bf16 bf16x4 __attribute__((ext_vector_type(4)));
typedef __bf16 bf16x8 __attribute__((ext_vector_type(8)));
typedef float f32x4 __attribute__((ext_vector_type(4)));
typedef float f32x16 __attribute__((ext_vector_type(16)));
typedef unsigned int uint4v __attribute__((ext_vector_type(4)));

// ---------------------------------------------------------------------------
// async global->LDS, 16B per lane. LDS dest must be wave-uniform base.
// ---------------------------------------------------------------------------
__device__ __forceinline__ void gld_lds16(const void* g, void* l) {
  __builtin_amdgcn_global_load_lds(
      (const __attribute__((address_space(1))) void*)g,
      (__attribute__((address_space(3))) void*)l, 16, 0, 0);
}

__device__ __forceinline__ unsigned pkbf(float a, float b) {
  union { bf16 h[2]; unsigned u; } x;
  x.h[0] = (bf16)a; x.h[1] = (bf16)b;
  return x.u;
}

// ---------------------------------------------------------------------------
// fp32 -> bf16 convert, 4 elems/thread
// ---------------------------------------------------------------------------
__global__ __launch_bounds__(256) void cvt_kernel(const float* __restrict__ src,
                                                  bf16* __restrict__ dst, int n4) {
  int i = blockIdx.x * 256 + threadIdx.x;
  if (i < n4) {
    float4 v = ((const float4*)src)[i];
    bf16x4 o = { (bf16)v.x, (bf16)v.y, (bf16)v.z, (bf16)v.w };
    ((bf16x4*)dst)[i] = o;
  }
}

// ---------------------------------------------------------------------------
// [R][C] fp32  ->  [C][R] bf16
// ---------------------------------------------------------------------------
__global__ __launch_bounds__(256) void transpose_cvt_kernel(const float* __restrict__ src,
                                                            bf16* __restrict__ dst,
                                                            int R, int C) {
  __shared__ float tile[32][33];
  int tx = threadIdx.x & 31, ty = threadIdx.x >> 5;
  int bx = blockIdx.x * 32, by = blockIdx.y * 32;
#pragma unroll
  for (int j = 0; j < 32; j += 8)
    tile[ty + j][tx] = src[(size_t)(by + ty + j) * C + bx + tx];
  __syncthreads();
#pragma unroll
  for (int j = 0; j < 32; j += 8)
    dst[(size_t)(bx + ty + j) * R + by + tx] = (bf16)tile[tx][ty + j];
}

// ---------------------------------------------------------------------------
// m97-structure GEMM (unchanged, passing): C[M,N] = A[M,K] * BT[N,K]^T
// ---------------------------------------------------------------------------
template <int MODE>
__global__ __launch_bounds__(256) void gemm_kernel(
    const bf16* __restrict__ A, const bf16* __restrict__ BT,
    float* __restrict__ Cf, bf16* __restrict__ qb, bf16* __restrict__ kb,
    bf16* __restrict__ vt, int M, int N, int K) {
  __shared__ bf16 As[128 * 32];
  __shared__ bf16 Bs[128 * 32];
  const int t = threadIdx.x;
  const int w = t >> 6, l = t & 63;
  const int bm = blockIdx.y * 128, bn = blockIdx.x * 128;
  const int wr = (w >> 1) * 64, wc = (w & 1) * 64;
  const int lr = l & 15, lh = l >> 4;
  f32x4 acc[4][4] = {};

  const bf16* Ab = A + (size_t)bm * K;
  const bf16* Bb = BT + (size_t)bn * K;
  const int srow = t >> 2;
  const int scol = (t & 3) * 8;
  char* AsB = (char*)As;
  char* BsB = (char*)Bs;
  const int ldsw = w * 1024;

  for (int k0 = 0; k0 < K; k0 += 32) {
    __syncthreads();
    gld_lds16(Ab + (size_t)srow * K + k0 + scol, AsB + ldsw);
    gld_lds16(Ab + (size_t)(srow + 64) * K + k0 + scol, AsB + 4096 + ldsw);
    gld_lds16(Bb + (size_t)srow * K + k0 + scol, BsB + ldsw);
    gld_lds16(Bb + (size_t)(srow + 64) * K + k0 + scol, BsB + 4096 + ldsw);
    __syncthreads();
    bf16x8 af[4], bfr[4];
#pragma unroll
    for (int m = 0; m < 4; ++m)
      af[m] = *(const bf16x8*)(AsB + (wr + m * 16 + lr) * 64 + lh * 16);
#pragma unroll
    for (int n = 0; n < 4; ++n)
      bfr[n] = *(const bf16x8*)(BsB + (wc + n * 16 + lr) * 64 + lh * 16);
#pragma unroll
    for (int m = 0; m < 4; ++m)
#pragma unroll
      for (int n = 0; n < 4; ++n)
        acc[m][n] = __builtin_amdgcn_mfma_f32_16x16x32_bf16(af[m], bfr[n],
                                                            acc[m][n], 0, 0, 0);
  }

  const int r0 = bm + wr + (lh << 2);
  const int c0 = bn + wc + lr;
#pragma unroll
  for (int m = 0; m < 4; ++m) {
#pragma unroll
    for (int n = 0; n < 4; ++n) {
#pragma unroll
      for (int r = 0; r < 4; ++r) {
        float v = acc[m][n][r];
        int row = r0 + m * 16 + r;
        int col = c0 + n * 16;
        if (MODE == 2) {
          Cf[(size_t)row * N + col] = v;
        } else {
          int bb = row >> 11, tt = row & 2047;
          if (col < 1024) {
            int h = col >> 6, d = col & 63;
            qb[(((size_t)(bb * 16 + h)) * 2048 + tt) * 64 + d] = (bf16)v;
          } else if (col < 2048) {
            int c = col - 1024, h = c >> 6, d = c & 63;
            kb[(((size_t)(bb * 16 + h)) * 2048 + tt) * 64 + d] = (bf16)v;
          } else {
            int c = col - 2048, h = c >> 6, d = c & 63;
            vt[(((size_t)(bb * 16 + h)) * 64 + d) * 2048 + tt] = (bf16)v;
          }
        }
      }
    }
  }
}

// ---------------------------------------------------------------------------
// Causal flash attention, swapped-QK^T 32x32x16 structure.
// grid 512 blocks (XCD-swizzled), 256 thr = 4 waves, wave = 32 q-rows.
// S^T = mfma(K,Q): lane owns full q-row (q = lane&31, 16 kv vals/lane).
// O^T = mfma(V^T, P^T): col = q = lane -> all softmax state lane-local.
// Softmax reduce: 15 local fmax + 1 shfl_xor(32). P^T frag via pack+shfl.
// K/V register double-buffer prefetch. Defer-max rescale (THR=8).
// ---------------------------------------------------------------------------
__global__ __launch_bounds__(256) void attn_kernel(const bf16* __restrict__ qb,
                                                   const bf16* __restrict__ kb,
                                                   const bf16* __restrict__ vt,
                                                   bf16* __restrict__ ao) {
  __shared__ bf16 plds[4][32][72];
  int wid = blockIdx.y * 16 + blockIdx.x;
  int swz = (wid & 7) * 64 + (wid >> 3);      // 4 heads per XCD -> K/V L2-resident
  const int bh = swz >> 4;
  const int q0 = (swz & 15) * 128;
  const int w = threadIdx.x >> 6, l = threadIdx.x & 63;
  const int qw = q0 + w * 32;
  const int lq = l & 31, hi = l >> 5;
  const bf16* Qh = qb + (size_t)bh * 2048 * 64;
  const bf16* Kh = kb + (size_t)bh * 2048 * 64;
  const bf16* Vh = vt + (size_t)bh * 64 * 2048;

  // Q B-frags (col=q=lq, k = c*16 + hi*8 + j), held for whole kernel
  bf16x8 qf[4];
#pragma unroll
  for (int c = 0; c < 4; ++c)
    qf[c] = *(const bf16x8*)(Qh + (size_t)(qw + lq) * 64 + c * 16 + hi * 8);

  f32x16 Ot0, Ot1;
#pragma unroll
  for (int r = 0; r < 16; ++r) { Ot0[r] = 0.f; Ot1[r] = 0.f; }
  float mrun = -1e30f, srun = 0.f;
  const int lastkt = qw >> 5;

  bf16x8 kA[4], vA[4], kB[4], vB[4];
#pragma unroll
  for (int c = 0; c < 4; ++c)
    kA[c] = *(const bf16x8*)(Kh + (size_t)lq * 64 + c * 16 + hi * 8);
#pragma unroll
  for (int df = 0; df < 2; ++df)
#pragma unroll
    for (int c = 0; c < 2; ++c)
      vA[df * 2 + c] = *(const bf16x8*)(Vh + (size_t)(df * 32 + lq) * 2048 + c * 16 + hi * 8);

  auto step = [&](bf16x8 (&KC)[4], bf16x8 (&VC)[4],
                  bf16x8 (&KN)[4], bf16x8 (&VN)[4], int kt) {
    const int kv0 = kt << 5;
    const int nkv0 = (kt < lastkt) ? kv0 + 32 : kv0;
    // prefetch next tile (overlaps with all compute below)
#pragma unroll
    for (int c = 0; c < 4; ++c)
      KN[c] = *(const bf16x8*)(Kh + (size_t)(nkv0 + lq) * 64 + c * 16 + hi * 8);
#pragma unroll
    for (int df = 0; df < 2; ++df)
#pragma unroll
      for (int c = 0; c < 2; ++c)
        VN[df * 2 + c] = *(const bf16x8*)(Vh + (size_t)(df * 32 + lq) * 2048 + nkv0 + c * 16 + hi * 8);

    // S^T[kv][q] = K-tile * Q-tile
    f32x16 S;
#pragma unroll
    for (int r = 0; r < 16; ++r) S[r] = 0.f;
#pragma unroll
    for (int c = 0; c < 4; ++c)
      S = __builtin_amdgcn_mfma_f32_32x32x16_bf16(KC[c], qf[c], S, 0, 0, 0);

    if (kt == lastkt) {  // causal mask on diagonal tile (kv0 == qw)
#pragma unroll
      for (int r = 0; r < 16; ++r) {
        int kvl = (r & 3) + 8 * (r >> 2) + 4 * hi;
        if (kvl > lq) S[r] = -1e30f;
      }
    }

    // row max: 15 local fmax + 1 shuffle (raw-score units; scale=0.125)
    float mx[8];
#pragma unroll
    for (int i = 0; i < 8; ++i) mx[i] = fmaxf(S[2 * i], S[2 * i + 1]);
#pragma unroll
    for (int i = 0; i < 4; ++i) mx[i] = fmaxf(mx[i], mx[i + 4]);
    mx[0] = fmaxf(mx[0], mx[2]); mx[1] = fmaxf(mx[1], mx[3]);
    float smax = fmaxf(mx[0], mx[1]);
    float vmax = fmaxf(smax, __shfl_xor(smax, 32, 64));

    float mn = mrun;
    if (!__all(vmax <= mrun + 64.0f)) {  // defer-max: 64 raw = 8 exp units
      mn = fmaxf(mrun, vmax);
      float al = __expf((mrun - mn) * 0.125f);
      srun *= al;
#pragma unroll
      for (int r = 0; r < 16; ++r) { Ot0[r] *= al; Ot1[r] *= al; }
      mrun = mn;
    }

    const float sc = 0.125f;
    const float nb = -mn * sc;
    float ps = 0.f;
    unsigned u_[8];
#pragma unroll
    for (int i = 0; i < 8; ++i) {
      float pa = __expf(fmaf(S[2 * i], sc, nb));
      float pb = __expf(fmaf(S[2 * i + 1], sc, nb));
      ps += pa + pb;
      u_[i] = pkbf(pa, pb);
    }
    ps += __shfl_xor(ps, 32, 64);
    srun += ps;

    unsigned s_[8];
#pragma unroll
    for (int i = 0; i < 8; ++i) s_[i] = __shfl_xor(u_[i], 32, 64);

    // P^T B-frags: chunk c covers kv_local 16c..16c+15, lane k = hi*8+j
    uint4v f0 = hi ? (uint4v){s_[2], s_[3], u_[2], u_[3]}
                   : (uint4v){u_[0], u_[1], s_[0], s_[1]};
    uint4v f1 = hi ? (uint4v){s_[6], s_[7], u_[6], u_[7]}
                   : (uint4v){u_[4], u_[5], s_[4], s_[5]};
    bf16x8 pf0 = __builtin_bit_cast(bf16x8, f0);
    bf16x8 pf1 = __builtin_bit_cast(bf16x8, f1);

    // O^T[d][q] += V^T * P^T
    Ot0 = __builtin_amdgcn_mfma_f32_32x32x16_bf16(VC[0], pf0, Ot0, 0, 0, 0);
    Ot0 = __builtin_amdgcn_mfma_f32_32x32x16_bf16(VC[1], pf1, Ot0, 0, 0, 0);
    Ot1 = __builtin_amdgcn_mfma_f32_32x32x16_bf16(VC[2], pf0, Ot1, 0, 0, 0);
    Ot1 = __builtin_amdgcn_mfma_f32_32x32x16_bf16(VC[3], pf1, Ot1, 0, 0, 0);
  };

  for (int kt = 0; kt <= lastkt; ++kt) {
    if ((kt & 1) == 0) step(kA, vA, kB, vB, kt);
    else               step(kB, vB, kA, vA, kt);
  }

  // epilogue: O^T -> LDS transpose -> coalesced 16B stores
  float inv = 1.0f / srun;
#pragma unroll
  for (int r = 0; r < 16; r += 2) {
    int d0 = (r & 3) + 8 * (r >> 2) + 4 * hi;
    *(unsigned*)&plds[w][lq][d0]      = pkbf(Ot0[r] * inv, Ot0[r + 1] * inv);
    *(unsigned*)&plds[w][lq][32 + d0] = pkbf(Ot1[r] * inv, Ot1[r + 1] * inv);
  }
  __syncthreads();

  const int bb = bh >> 4, h = bh & 15;
  const int q = l >> 1, dh = (l & 1) * 32;
  size_t orow = ((size_t)(bb * 2048 + qw + q)) * 1024 + h * 64 + dh;
#pragma unroll
  for (int c = 0; c < 4; ++c) {
    bf16x8 vv = *(const bf16x8*)&plds[w][q][dh + c * 8];
    *(bf16x8*)(ao + orow + c * 8) = vv;
  }
}

// ---------------------------------------------------------------------------
// launch
// ---------------------------------------------------------------------------
extern "C" void kernel_launch(void* const* d_in, const int* in_sizes, int n_in,
                              void* d_out, int out_size, void* d_ws, size_t ws_size,
                              hipStream_t stream) {
  const float* x = (const float*)d_in[0];
  // d_in[1] = causal mask — implemented analytically
  const float* Wqkv = (const float*)d_in[2];
  const float* Wout = (const float*)d_in[3];
  float* out = (float*)d_out;

  char* ws = (char*)d_ws;
  bf16* xb  = (bf16*)(ws);
  bf16* wqT = (bf16*)(ws + (size_t)(8 << 20));
  bf16* woT = (bf16*)(ws + (size_t)(14 << 20));
  bf16* qb  = (bf16*)(ws + (size_t)(16 << 20));
  bf16* kb  = (bf16*)(ws + (size_t)(24 << 20));
  bf16* vt  = (bf16*)(ws + (size_t)(32 << 20));
  bf16* ao  = (bf16*)(ws + (size_t)(40 << 20));

  cvt_kernel<<<dim3(4096), dim3(256), 0, stream>>>(x, xb, 1048576);
  transpose_cvt_kernel<<<dim3(96, 32), dim3(256), 0, stream>>>(Wqkv, wqT, 1024, 3072);
  transpose_cvt_kernel<<<dim3(32, 32), dim3(256), 0, stream>>>(Wout, woT, 1024, 1024);
  gemm_kernel<1><<<dim3(24, 32), dim3(256), 0, stream>>>(xb, wqT, nullptr, qb, kb, vt,
                                                         4096, 3072, 1024);
  attn_kernel<<<dim3(16, 32), dim3(256), 0, stream>>>(qb, kb, vt, ao);
  gemm_kernel<2><<<dim3(8, 32), dim3(256), 0, stream>>>(ao, woT, out, nullptr, nullptr,
                                                        nullptr, 4096, 1024, 1024);
}